// Round 1
// baseline (260.433 us; speedup 1.0000x reference)
//
#include <hip/hip_runtime.h>
#include <cstdint>

#define DEV __device__ __forceinline__

typedef float f32x4 __attribute__((ext_vector_type(4)));
typedef short s16x8 __attribute__((ext_vector_type(8)));

DEV unsigned short f2bf(float f){
    unsigned u = __builtin_bit_cast(unsigned, f);
    u = u + 0x7fffu + ((u >> 16) & 1u);   // RNE
    return (unsigned short)(u >> 16);
}
DEV float bf2f(unsigned short h){
    unsigned u = ((unsigned)h) << 16;
    return __builtin_bit_cast(float, u);
}

typedef const void __attribute__((address_space(1)))* gcp;
typedef void __attribute__((address_space(3)))* lp;
DEV void gload_lds16(const void* g, void* l){
    // async global->LDS, 16B per lane; LDS dest = wave-uniform base + lane*16
    __builtin_amdgcn_global_load_lds((gcp)g, (lp)l, 16, 0, 0);
}

// raw barrier: NO vmcnt drain (that's the whole point); asm memory clobber
// gives compiler-level ordering for the surrounding LDS/global ops.
DEV void bar(){ asm volatile("s_barrier" ::: "memory"); }
DEV void lgkm0(){ asm volatile("s_waitcnt lgkmcnt(0)" ::: "memory"); }
#define WAIT_VM(n) asm volatile("s_waitcnt vmcnt(" #n ")" ::: "memory")
#define MFMA16(a,b,c) __builtin_amdgcn_mfma_f32_16x16x32_bf16(a,b,c,0,0,0)

// ---------------------------------------------------------------------------
// Stage 1 (grid 4097):
//   block 0        : dragon pattern + blend scalar
//   blocks 1..2048 : Q -> bf16
//   blocks 2049..  : V -> Vt (bf16 [b][d][s]) + race-free vmean partials
// ---------------------------------------------------------------------------
__global__ __launch_bounds__(256) void k_stage1(
    const float* __restrict__ Q, const float* __restrict__ V,
    const float* __restrict__ scale, const float* __restrict__ bias,
    const float* __restrict__ w1, const float* __restrict__ b1,
    const float* __restrict__ w2, const float* __restrict__ b2,
    float* __restrict__ dragon_w, float* __restrict__ blend_out,
    unsigned short* __restrict__ Qb, unsigned short* __restrict__ Vt,
    float* __restrict__ vmean_part)
{
    __shared__ float sh[8704];
    int tid = threadIdx.x;
    int bx  = blockIdx.x;

    if (bx == 0){
        float* A    = sh;          // 4096
        float* Bb   = sh + 4096;   // 4096
        float* sred = sh + 8192;   // 512
        if (tid == 0) A[0] = 0.5f;
        __syncthreads();
        int len = 1;
        for (int it = 1; it < 12; ++it){
            int n = len, nl = 2*n + 1;
            for (int i = tid; i < nl; i += 256){
                float v;
                if (i < n)       v = A[i];
                else if (i == n) v = 0.5f;
                else             v = 1.0f - A[2*n - i];
                Bb[i] = v;
            }
            __syncthreads();
            const float third = 1.0f/3.0f;
            for (int i = tid; i < nl; i += 256){
                float s = Bb[i]*third;
                if (i > 0)    s += Bb[i-1]*third;
                if (i < nl-1) s += Bb[i+1]*third;
                A[i] = s;
            }
            __syncthreads();
            float mn = 3.4e38f, mx = -3.4e38f;
            for (int i = tid; i < nl; i += 256){ float v = A[i]; mn = fminf(mn,v); mx = fmaxf(mx,v); }
            sred[tid] = mn; sred[256 + tid] = mx;
            __syncthreads();
            for (int off = 128; off > 0; off >>= 1){
                if (tid < off){
                    sred[tid]       = fminf(sred[tid],       sred[tid+off]);
                    sred[256 + tid] = fmaxf(sred[256 + tid], sred[256 + tid + off]);
                }
                __syncthreads();
            }
            float lo = sred[0], den = sred[256] - lo + 1e-8f;
            for (int i = tid; i < nl; i += 256) A[i] = (A[i] - lo) / den;
            len = nl;
            __syncthreads();
        }
        float sc = scale[11], bi = bias[11];
        for (int i = tid; i < 2048; i += 256){
            float x = A[2*i]*sc + bi;
            dragon_w[i] = fmaxf(x, 0.f) + log1pf(__expf(-fabsf(x)));  // softplus
        }
        if (tid < 64){
            float h = fmaxf(w1[11*64 + tid] + b1[tid], 0.f);
            float c = h * w2[tid];
            for (int off = 32; off > 0; off >>= 1) c += __shfl_xor(c, off, 64);
            if (tid == 0) blend_out[0] = 1.f/(1.f + __expf(-(c + b2[0])));
        }
        return;
    }

    if (bx <= 2048){
        const long long total4 = (long long)8*2048*512/4;
        long long stride = 2048LL*256;
        for (long long i = (long long)(bx-1)*256 + tid; i < total4; i += stride){
            long long base = i*4;
            const float4 q = *(const float4*)(Q + base);
            ushort4 qo;
            qo.x = f2bf(q.x); qo.y = f2bf(q.y); qo.z = f2bf(q.z); qo.w = f2bf(q.w);
            *(ushort4*)(Qb + base) = qo;
        }
        return;
    }

    int t = bx - 2049;
    int stile = t & 31, dtile = (t >> 5) & 7, b = t >> 8;
    int s0 = stile*64, d0 = dtile*64;
    float (*tile)[66] = (float(*)[66])sh;
    float* red = sh + 4352;
    int tx = tid & 63, ty = tid >> 6;
    const float* src = V + ((long long)b*2048 + s0)*512 + d0;
    #pragma unroll
    for (int r = 0; r < 16; ++r){
        int row = r*4 + ty;
        tile[row][tx] = src[(long long)row*512 + tx];
    }
    __syncthreads();
    unsigned short* dst = Vt + ((long long)b*512 + d0)*2048 + s0;
    #pragma unroll
    for (int r = 0; r < 16; ++r){
        int drow = r*4 + ty;
        dst[(long long)drow*2048 + tx] = f2bf(tile[tx][drow]);
    }
    int dcol = tid & 63, sp = tid >> 6;
    float s = 0.f;
    #pragma unroll
    for (int ii = 0; ii < 16; ++ii) s += tile[sp*16 + ii][dcol];
    red[sp*64 + dcol] = s;
    __syncthreads();
    if (sp == 0){
        float tot = red[dcol] + red[64+dcol] + red[128+dcol] + red[192+dcol];
        vmean_part[stile*4096 + b*512 + d0 + dcol] = tot * (1.0f/2048.0f);
    }
}

// ---------------------------------------------------------------------------
// Stage 2 (grid 2064): blocks 0..15 reduce vmean partials; rest: K*w -> bf16
// ---------------------------------------------------------------------------
__global__ __launch_bounds__(256) void k_stage2(
    const float* __restrict__ K, const float* __restrict__ dragon_w,
    const float* __restrict__ vmean_part,
    unsigned short* __restrict__ Kb, float* __restrict__ vmean)
{
    int bx = blockIdx.x, tid = threadIdx.x;
    if (bx < 16){
        int idx = bx*256 + tid;
        float s = 0.f;
        #pragma unroll
        for (int st = 0; st < 32; ++st) s += vmean_part[st*4096 + idx];
        vmean[idx] = s;
        return;
    }
    const long long total4 = (long long)8*2048*512/4;
    long long stride = 2048LL*256;
    for (long long i = (long long)(bx-16)*256 + tid; i < total4; i += stride){
        long long base = i*4;
        int s = (int)((base >> 9) & 2047);
        float w = dragon_w[s];
        const float4 k = *(const float4*)(K + base);
        ushort4 ko;
        ko.x = f2bf(k.x*w); ko.y = f2bf(k.y*w); ko.z = f2bf(k.z*w); ko.w = f2bf(k.w*w);
        *(ushort4*)(Kb + base) = ko;
    }
}

// ---------------------------------------------------------------------------
// GEMM 1: Sp[b,q,k] = bf16( exp( (Qb . Kb^T) / sqrt(512) ) ), plus per-k-block
// row sums lpart[b][kb][q] for the softmax denominator.
//
// 256x256 tile, BK=64, 8 waves (2M x 4N), per-wave 128x64 (8x4 MFMA frags).
// Pipelined schedule (T2+T3+T4+T5): LDS = ring of 4 half-tile slots per
// operand (half = 128 rows x 64 cols, 16 KiB); 4 phases per K-tile, each
// phase = {ds_read subtile, 1 half-tile global_load_lds prefetch, s_barrier,
// lgkmcnt(0), setprio(1), 16 MFMA, setprio(0), s_barrier}. Counted
// s_waitcnt vmcnt(4) once per K-tile (never 0 in the loop): tile t+1's A is
// staged in t.ph1/ph2, tile t+2's B in t.ph3/ph4, so at t.ph4 exactly 4
// loads (t.ph3+t.ph4) may stay in flight. Slot-free proof: a slot's last
// ds_read issues in phase p, retires at p's lgkmcnt(0) before p's trailing
// barrier; its re-stage is issued in a later phase. Tail stages use modulo
// tile indices (harmless loads into dead slots) so vmcnt immediates stay
// exact; vmcnt(0)+barrier before the epilogue reuses LDS.
// XOR swizzle as before: LDS (row, chunk c) holds global chunk c^(row&7).
// ---------------------------------------------------------------------------
#define SCALE_QK 0.04419417382415922f

__global__ __launch_bounds__(512, 2) void k_gemm_qk(
    const unsigned short* __restrict__ Qb, const unsigned short* __restrict__ Kb,
    unsigned short* __restrict__ Sp, float* __restrict__ lpart)
{
    __shared__ unsigned short At[4*8192];   // 4 slots x (128 x 64) = 64 KiB
    __shared__ unsigned short Bt[4*8192];   // 64 KiB
    const int tid  = threadIdx.x;
    const int lane = tid & 63, wave = tid >> 6;
    const int wm = wave >> 2, wn = wave & 3;        // 2 x 4 waves
    const int ln = lane & 15, q4 = lane >> 4;
    const int q0 = blockIdx.y*256, k0 = blockIdx.x*256, b = blockIdx.z;
    const unsigned short* Ab = Qb + ((long long)b*2048 + q0)*512;
    const unsigned short* Bb = Kb + ((long long)b*2048 + k0)*512;
    const int cc = lane & 7, rg = lane >> 3;
    const int gcx = cc ^ rg;                 // pre-swizzled source chunk
    const int ch0 = wave*2, ch1 = wave*2 + 1;

    f32x4 acc[8][4];
    #pragma unroll
    for (int m = 0; m < 8; ++m)
        #pragma unroll
        for (int n = 0; n < 4; ++n) acc[m][n] = (f32x4)0.f;

    s16x8 af[8], b0[4], b1[4];

    auto STA = [&](int kt, int h){
        unsigned short* d = &At[(((kt<<1) + h) & 3) * 8192];
        const unsigned short* s = Ab + (long long)(h*128)*512 + kt*64 + gcx*8;
        gload_lds16(s + (long long)(ch0*8 + rg)*512, d + ch0*512);
        gload_lds16(s + (long long)(ch1*8 + rg)*512, d + ch1*512);
    };
    auto STB = [&](int kt, int h){
        unsigned short* d = &Bt[(((kt<<1) + h) & 3) * 8192];
        const unsigned short* s = Bb + (long long)(h*128)*512 + kt*64 + gcx*8;
        gload_lds16(s + (long long)(ch0*8 + rg)*512, d + ch0*512);
        gload_lds16(s + (long long)(ch1*8 + rg)*512, d + ch1*512);
    };
    auto LDA = [&](int t, int ks){
        const unsigned short* base = &At[(((t<<1) + wm) & 3) * 8192];
        const int ccs = ((ks*4 + q4) ^ (ln & 7)) * 8;
        #pragma unroll
        for (int m = 0; m < 8; ++m)
            af[m] = *(const s16x8*)&base[(m*16 + ln)*64 + ccs];
    };
    auto LDB = [&](int t, int ks, s16x8* bv){
        const unsigned short* base = &Bt[(((t<<1) + (wn>>1)) & 3) * 8192];
        const int ccs = ((ks*4 + q4) ^ (ln & 7)) * 8;
        #pragma unroll
        for (int n = 0; n < 4; ++n)
            bv[n] = *(const s16x8*)&base[((wn&1)*64 + n*16 + ln)*64 + ccs];
    };

    // prologue: B(0), A(0), B(1) staged; allow B(1)'s 4 loads to stay in flight
    STB(0,0); STB(0,1); STA(0,0); STA(0,1); STB(1,0); STB(1,1);
    WAIT_VM(4);
    bar();

    for (int t = 0; t < 8; ++t){
        const int t1 = (t+1) & 7, t2 = (t+2) & 7;
        // ---- ph1: reads a-ks0 + b-ks0; stage A-h0(t+1); MFMA ks0 x n0,n1
        LDA(t, 0); LDB(t, 0, b0);
        STA(t1, 0);
        bar(); lgkm0();
        __builtin_amdgcn_s_setprio(1);
        #pragma unroll
        for (int m = 0; m < 8; ++m){
            acc[m][0] = MFMA16(af[m], b0[0], acc[m][0]);
            acc[m][1] = MFMA16(af[m], b0[1], acc[m][1]);
        }
        __builtin_amdgcn_s_setprio(0);
        bar();
        // ---- ph2: reads b-ks1; stage A-h1(t+1); MFMA ks0 x n2,n3
        LDB(t, 1, b1);
        STA(t1, 1);
        bar(); lgkm0();
        __builtin_amdgcn_s_setprio(1);
        #pragma unroll
        for (int m = 0; m < 8; ++m){
            acc[m][2] = MFMA16(af[m], b0[2], acc[m][2]);
            acc[m][3] = MFMA16(af[m], b0[3], acc[m][3]);
        }
        __builtin_amdgcn_s_setprio(0);
        bar();
        // ---- ph3: reads a-ks1; stage B-h0(t+2); MFMA ks1 x n0,n1
        LDA(t, 1);
        STB(t2, 0);
        bar(); lgkm0();
        __builtin_amdgcn_s_setprio(1);
        #pragma unroll
        for (int m = 0; m < 8; ++m){
            acc[m][0] = MFMA16(af[m], b1[0], acc[m][0]);
            acc[m][1] = MFMA16(af[m], b1[1], acc[m][1]);
        }
        __builtin_amdgcn_s_setprio(0);
        bar();
        // ---- ph4: stage B-h1(t+2); vmcnt(4) = ph3+ph4 loads may stay in flight
        STB(t2, 1);
        WAIT_VM(4);
        bar();
        __builtin_amdgcn_s_setprio(1);
        #pragma unroll
        for (int m = 0; m < 8; ++m){
            acc[m][2] = MFMA16(af[m], b1[2], acc[m][2]);
            acc[m][3] = MFMA16(af[m], b1[3], acc[m][3]);
        }
        __builtin_amdgcn_s_setprio(0);
        bar();
    }
    WAIT_VM(0);   // drain dummy tail stages before LDS reuse
    bar();

    // epilogue: exp, bf16 store, and per-k-block row sums of the ROUNDED
    // values (matches what PV will actually sum, same numerics as before)
    float* lred = (float*)At;               // [256][4]
    unsigned short* outp = Sp + (long long)b*2048*2048 + (long long)q0*2048 + k0;
    #pragma unroll
    for (int m = 0; m < 8; ++m){
        float rs[4] = {0.f, 0.f, 0.f, 0.f};
        #pragma unroll
        for (int r = 0; r < 4; ++r){
            int qrow = wm*128 + m*16 + q4*4 + r;
            #pragma unroll
            for (int n = 0; n < 4; ++n){
                int kcol = wn*64 + n*16 + ln;
                float v = __expf(acc[m][n][r] * SCALE_QK);
                unsigned short h = f2bf(v);
                outp[(long long)qrow*2048 + kcol] = h;
                rs[r] += bf2f(h);
            }
        }
        #pragma unroll
        for (int r = 0; r < 4; ++r){
            float v = rs[r];
            v += __shfl_xor(v, 1, 16);
            v += __shfl_xor(v, 2, 16);
            v += __shfl_xor(v, 4, 16);
            v += __shfl_xor(v, 8, 16);
            if (ln == 0) lred[(wm*128 + m*16 + q4*4 + r)*4 + wn] = v;
        }
    }
    bar();
    if (tid < 256){
        float lpv = lred[tid*4+0] + lred[tid*4+1] + lred[tid*4+2] + lred[tid*4+3];
        lpart[((long long)b*8 + blockIdx.x)*2048 + q0 + tid] = lpv;
    }
}

// ---------------------------------------------------------------------------
// GEMM 2: out[b,q,d] = blend * (Sp . V) / l[q] + (1-blend) * Vmean[d]
// 256x128 tile (grid (4,8,8) = exactly 1 block/CU), BK=64, 8 waves (4M x 2N),
// per-wave 64x64 (4x4 frags). Same ring-pipelined schedule as k_gemm_qk,
// vmcnt(2) once per K-tile (B halves are 1 load each). l[q] comes from lpart
// (no per-loop lsum work in the GEMM anymore).
// ---------------------------------------------------------------------------
__global__ __launch_bounds__(512, 2) void k_gemm_pv(
    const unsigned short* __restrict__ Sp, const unsigned short* __restrict__ Vt,
    const float* __restrict__ lpart, const float* __restrict__ vmean,
    const float* __restrict__ blendp, float* __restrict__ out)
{
    __shared__ unsigned short At[4*8192];   // 4 slots x (128 x 64) = 64 KiB
    __shared__ unsigned short Bt[4*4096];   // 4 slots x ( 64 x 64) = 32 KiB
    const int tid  = threadIdx.x;
    const int lane = tid & 63, wave = tid >> 6;
    const int wm = wave & 3, wn = wave >> 2;        // 4 x 2 waves
    const int ln = lane & 15, q4 = lane >> 4;
    const int q0 = blockIdx.y*256, d0 = blockIdx.x*128, b = blockIdx.z;
    const unsigned short* Ab = Sp + (long long)b*2048*2048 + (long long)q0*2048;
    const unsigned short* Bb = Vt + ((long long)b*512 + d0)*2048;
    const int cc = lane & 7, rg = lane >> 3;
    const int gcx = cc ^ rg;
    const int ch0 = wave*2, ch1 = wave*2 + 1;

    f32x4 acc[4][4];
    #pragma unroll
    for (int m = 0; m < 4; ++m)
        #pragma unroll
        for (int n = 0; n < 4; ++n) acc[m][n] = (f32x4)0.f;

    s16x8 af[4], b0[4], b1[4];

    auto STA = [&](int kt, int h){
        unsigned short* d = &At[(((kt<<1) + h) & 3) * 8192];
        const unsigned short* s = Ab + (long long)(h*128)*2048 + kt*64 + gcx*8;
        gload_lds16(s + (long long)(ch0*8 + rg)*2048, d + ch0*512);
        gload_lds16(s + (long long)(ch1*8 + rg)*2048, d + ch1*512);
    };
    auto STB = [&](int kt, int h){
        unsigned short* d = &Bt[(((kt<<1) + h) & 3) * 4096];
        const unsigned short* s = Bb + (long long)(h*64 + wave*8 + rg)*2048 + kt*64 + gcx*8;
        gload_lds16(s, d + wave*512);
    };
    auto LDA = [&](int t, int ks){
        const unsigned short* base = &At[(((t<<1) + (wm>>1)) & 3) * 8192];
        const int ccs = ((ks*4 + q4) ^ (ln & 7)) * 8;
        #pragma unroll
        for (int m = 0; m < 4; ++m)
            af[m] = *(const s16x8*)&base[((wm&1)*64 + m*16 + ln)*64 + ccs];
    };
    auto LDB = [&](int t, int ks, s16x8* bv){
        const unsigned short* base = &Bt[(((t<<1) + wn) & 3) * 4096];
        const int ccs = ((ks*4 + q4) ^ (ln & 7)) * 8;
        #pragma unroll
        for (int n = 0; n < 4; ++n)
            bv[n] = *(const s16x8*)&base[(n*16 + ln)*64 + ccs];
    };

    // prologue
    STB(0,0); STB(0,1); STA(0,0); STA(0,1); STB(1,0); STB(1,1);
    WAIT_VM(2);
    bar();

    for (int t = 0; t < 32; ++t){
        const int t1 = (t+1) & 31, t2 = (t+2) & 31;
        // ---- ph1: reads a-ks0 + b-ks0 (full); stage A-h0(t+1); MFMA ks0 x n0,n1
        LDA(t, 0); LDB(t, 0, b0);
        STA(t1, 0);
        bar(); lgkm0();
        __builtin_amdgcn_s_setprio(1);
        #pragma unroll
        for (int m = 0; m < 4; ++m){
            acc[m][0] = MFMA16(af[m], b0[0], acc[m][0]);
            acc[m][1] = MFMA16(af[m], b0[1], acc[m][1]);
        }
        __builtin_amdgcn_s_setprio(0);
        bar();
        // ---- ph2: stage A-h1(t+1); MFMA ks0 x n2,n3
        STA(t1, 1);
        bar();
        __builtin_amdgcn_s_setprio(1);
        #pragma unroll
        for (int m = 0; m < 4; ++m){
            acc[m][2] = MFMA16(af[m], b0[2], acc[m][2]);
            acc[m][3] = MFMA16(af[m], b0[3], acc[m][3]);
        }
        __builtin_amdgcn_s_setprio(0);
        bar();
        // ---- ph3: reads a-ks1 + b-ks1 (full); MFMA ks1 x n0,n1
        LDA(t, 1); LDB(t, 1, b1);
        bar(); lgkm0();
        __builtin_amdgcn_s_setprio(1);
        #pragma unroll
        for (int m = 0; m < 4; ++m){
            acc[m][0] = MFMA16(af[m], b1[0], acc[m][0]);
            acc[m][1] = MFMA16(af[m], b1[1], acc[m][1]);
        }
        __builtin_amdgcn_s_setprio(0);
        bar();
        // ---- ph4: stage B-h0+h1(t+2) (slots freed by ph3's lgkm0); vmcnt(2)
        STB(t2, 0); STB(t2, 1);
        WAIT_VM(2);
        bar();
        __builtin_amdgcn_s_setprio(1);
        #pragma unroll
        for (int m = 0; m < 4; ++m){
            acc[m][2] = MFMA16(af[m], b1[2], acc[m][2]);
            acc[m][3] = MFMA16(af[m], b1[3], acc[m][3]);
        }
        __builtin_amdgcn_s_setprio(0);
        bar();
    }
    WAIT_VM(0);
    bar();

    // l[q] from per-k-block partials, then blended epilogue
    float* l_sh = (float*)Bt;   // 256 floats
    if (tid < 256){
        float s = 0.f;
        #pragma unroll
        for (int kb = 0; kb < 8; ++kb)
            s += lpart[((long long)b*8 + kb)*2048 + q0 + tid];
        l_sh[tid] = 1.0f / s;
    }
    bar();

    float blend = blendp[0];
    float ib = 1.0f - blend;
    float* obase = out + ((long long)b*2048 + q0)*512 + d0;
    float vm[4];
    #pragma unroll
    for (int n = 0; n < 4; ++n) vm[n] = vmean[b*512 + d0 + wn*64 + n*16 + ln];
    #pragma unroll
    for (int m = 0; m < 4; ++m){
        #pragma unroll
        for (int r = 0; r < 4; ++r){
            int ql = wm*64 + m*16 + q4*4 + r;
            float linv = l_sh[ql];
            #pragma unroll
            for (int n = 0; n < 4; ++n){
                int dl = wn*64 + n*16 + ln;
                obase[(long long)ql*512 + dl] = blend*acc[m][n][r]*linv + ib*vm[n];
            }
        }
    }
}

// ---------------------------------------------------------------------------
extern "C" void kernel_launch(void* const* d_in, const int* in_sizes, int n_in,
                              void* d_out, int out_size, void* d_ws, size_t ws_size,
                              hipStream_t stream)
{
    (void)in_sizes; (void)n_in; (void)out_size; (void)ws_size;
    const float* Q  = (const float*)d_in[0];
    const float* K  = (const float*)d_in[1];
    const float* V  = (const float*)d_in[2];
    const float* ps = (const float*)d_in[3];
    const float* pb = (const float*)d_in[4];
    const float* w1 = (const float*)d_in[5];
    const float* b1 = (const float*)d_in[6];
    const float* w2 = (const float*)d_in[7];
    const float* b2 = (const float*)d_in[8];
    float* out = (float*)d_out;

    char* ws = (char*)d_ws;
    float* dragon_w        = (float*)(ws);                                        // 8 KiB
    float* blend           = (float*)(ws + 8192);
    float* vmean           = (float*)(ws + 16384);                                // 16 KiB
    float* vmean_part      = (float*)(ws + 32768);                                // 512 KiB (reused as lpart)
    size_t off = 32768 + (size_t)512*1024;
    unsigned short* Qb     = (unsigned short*)(ws + off);                         // 16 MiB
    unsigned short* Kb     = (unsigned short*)(ws + off + (size_t)16*1024*1024);  // 16 MiB
    unsigned short* Vt     = (unsigned short*)(ws + off + (size_t)32*1024*1024);  // 16 MiB
    unsigned short* Sp     = (unsigned short*)(ws + off + (size_t)48*1024*1024);  // 64 MiB
    float* lpart           = vmean_part;  // stage2 consumed it before gemm_qk runs

    hipLaunchKernelGGL(k_stage1,  dim3(4097),     dim3(256), 0, stream,
                       Q, V, ps, pb, w1, b1, w2, b2, dragon_w, blend, Qb, Vt, vmean_part);
    hipLaunchKernelGGL(k_stage2,  dim3(2064),     dim3(256), 0, stream,
                       K, dragon_w, vmean_part, Kb, vmean);
    hipLaunchKernelGGL(k_gemm_qk, dim3(8, 8, 8),  dim3(512), 0, stream,
                       Qb, Kb, Sp, lpart);
    hipLaunchKernelGGL(k_gemm_pv, dim3(4, 8, 8),  dim3(512), 0, stream,
                       Sp, Vt, lpart, vmean, blend, out);
}

// Round 2
// 255.887 us; speedup vs baseline: 1.0178x; 1.0178x over previous
//
#include <hip/hip_runtime.h>
#include <cstdint>

#define DEV __device__ __forceinline__

typedef float f32x4 __attribute__((ext_vector_type(4)));
typedef short s16x8 __attribute__((ext_vector_type(8)));

DEV unsigned short f2bf(float f){
    unsigned u = __builtin_bit_cast(unsigned, f);
    u = u + 0x7fffu + ((u >> 16) & 1u);   // RNE
    return (unsigned short)(u >> 16);
}
DEV float bf2f(unsigned short h){
    unsigned u = ((unsigned)h) << 16;
    return __builtin_bit_cast(float, u);
}

typedef const void __attribute__((address_space(1)))* gcp;
typedef void __attribute__((address_space(3)))* lp;
DEV void gload_lds16(const void* g, void* l){
    // async global->LDS, 16B per lane; LDS dest = wave-uniform base + lane*16
    __builtin_amdgcn_global_load_lds((gcp)g, (lp)l, 16, 0, 0);
}

// ---------------------------------------------------------------------------
// Stage 1 (grid 4097):
//   block 0        : dragon pattern + blend scalar
//   blocks 1..2048 : Q -> bf16
//   blocks 2049..  : V -> Vt (bf16 [b][d][s]) + race-free vmean partials
//                    (float4 loads / ushort4 stores; pad 67 -> both LDS access
//                     patterns are 2-way aliasing = free)
// ---------------------------------------------------------------------------
__global__ __launch_bounds__(256) void k_stage1(
    const float* __restrict__ Q, const float* __restrict__ V,
    const float* __restrict__ scale, const float* __restrict__ bias,
    const float* __restrict__ w1, const float* __restrict__ b1,
    const float* __restrict__ w2, const float* __restrict__ b2,
    float* __restrict__ dragon_w, float* __restrict__ blend_out,
    unsigned short* __restrict__ Qb, unsigned short* __restrict__ Vt,
    float* __restrict__ vmean_part)
{
    __shared__ float sh[8704];
    int tid = threadIdx.x;
    int bx  = blockIdx.x;

    if (bx == 0){
        float* A    = sh;          // 4096
        float* Bb   = sh + 4096;   // 4096
        float* sred = sh + 8192;   // 512
        if (tid == 0) A[0] = 0.5f;
        __syncthreads();
        int len = 1;
        for (int it = 1; it < 12; ++it){
            int n = len, nl = 2*n + 1;
            for (int i = tid; i < nl; i += 256){
                float v;
                if (i < n)       v = A[i];
                else if (i == n) v = 0.5f;
                else             v = 1.0f - A[2*n - i];
                Bb[i] = v;
            }
            __syncthreads();
            const float third = 1.0f/3.0f;
            for (int i = tid; i < nl; i += 256){
                float s = Bb[i]*third;
                if (i > 0)    s += Bb[i-1]*third;
                if (i < nl-1) s += Bb[i+1]*third;
                A[i] = s;
            }
            __syncthreads();
            float mn = 3.4e38f, mx = -3.4e38f;
            for (int i = tid; i < nl; i += 256){ float v = A[i]; mn = fminf(mn,v); mx = fmaxf(mx,v); }
            sred[tid] = mn; sred[256 + tid] = mx;
            __syncthreads();
            for (int off = 128; off > 0; off >>= 1){
                if (tid < off){
                    sred[tid]       = fminf(sred[tid],       sred[tid+off]);
                    sred[256 + tid] = fmaxf(sred[256 + tid], sred[256 + tid + off]);
                }
                __syncthreads();
            }
            float lo = sred[0], den = sred[256] - lo + 1e-8f;
            for (int i = tid; i < nl; i += 256) A[i] = (A[i] - lo) / den;
            len = nl;
            __syncthreads();
        }
        float sc = scale[11], bi = bias[11];
        for (int i = tid; i < 2048; i += 256){
            float x = A[2*i]*sc + bi;
            dragon_w[i] = fmaxf(x, 0.f) + log1pf(__expf(-fabsf(x)));  // softplus
        }
        if (tid < 64){
            float h = fmaxf(w1[11*64 + tid] + b1[tid], 0.f);
            float c = h * w2[tid];
            for (int off = 32; off > 0; off >>= 1) c += __shfl_xor(c, off, 64);
            if (tid == 0) blend_out[0] = 1.f/(1.f + __expf(-(c + b2[0])));
        }
        return;
    }

    if (bx <= 2048){
        const long long total4 = (long long)8*2048*512/4;
        long long stride = 2048LL*256;
        for (long long i = (long long)(bx-1)*256 + tid; i < total4; i += stride){
            long long base = i*4;
            const float4 q = *(const float4*)(Q + base);
            ushort4 qo;
            qo.x = f2bf(q.x); qo.y = f2bf(q.y); qo.z = f2bf(q.z); qo.w = f2bf(q.w);
            *(ushort4*)(Qb + base) = qo;
        }
        return;
    }

    // ---- V transpose + vmean partials ----
    int t = bx - 2049;                    // 0..2047 = 32 stile x 8 dtile x 8 b
    int stile = t & 31, dtile = (t >> 5) & 7, b = t >> 8;
    int s0 = stile*64, d0 = dtile*64;
    float (*tile)[67] = (float(*)[67])sh;  // 64x67 floats = 4288
    float* red = sh + 4288;                // 256 floats
    int c4 = tid & 15, rr = tid >> 4;
    const float* src = V + ((long long)b*2048 + s0)*512 + d0;
    #pragma unroll
    for (int p = 0; p < 4; ++p){
        int row = p*16 + rr;
        const float4 v = *(const float4*)(src + (long long)row*512 + c4*4);
        tile[row][c4*4+0] = v.x; tile[row][c4*4+1] = v.y;
        tile[row][c4*4+2] = v.z; tile[row][c4*4+3] = v.w;
    }
    __syncthreads();
    unsigned short* dst = Vt + ((long long)b*512 + d0)*2048 + s0;
    #pragma unroll
    for (int p = 0; p < 4; ++p){
        int d = p*16 + rr;
        ushort4 o;
        o.x = f2bf(tile[c4*4+0][d]);
        o.y = f2bf(tile[c4*4+1][d]);
        o.z = f2bf(tile[c4*4+2][d]);
        o.w = f2bf(tile[c4*4+3][d]);
        *(ushort4*)(dst + (long long)d*2048 + c4*4) = o;
    }
    // vmean partial: per-wave one s-row-group, contiguous dcol reads (free)
    int dcol = tid & 63, sp = tid >> 6;
    float s = 0.f;
    #pragma unroll
    for (int ii = 0; ii < 16; ++ii) s += tile[sp*16 + ii][dcol];
    red[sp*64 + dcol] = s;
    __syncthreads();
    if (sp == 0){
        float tot = red[dcol] + red[64+dcol] + red[128+dcol] + red[192+dcol];
        vmean_part[stile*4096 + b*512 + d0 + dcol] = tot * (1.0f/2048.0f);
    }
}

// ---------------------------------------------------------------------------
// Stage 2 (grid 2064): blocks 0..15 reduce vmean partials; rest: K*w -> bf16
// ---------------------------------------------------------------------------
__global__ __launch_bounds__(256) void k_stage2(
    const float* __restrict__ K, const float* __restrict__ dragon_w,
    const float* __restrict__ vmean_part,
    unsigned short* __restrict__ Kb, float* __restrict__ vmean)
{
    int bx = blockIdx.x, tid = threadIdx.x;
    if (bx < 16){
        int idx = bx*256 + tid;
        float s = 0.f;
        #pragma unroll
        for (int st = 0; st < 32; ++st) s += vmean_part[st*4096 + idx];
        vmean[idx] = s;
        return;
    }
    const long long total4 = (long long)8*2048*512/4;
    long long stride = 2048LL*256;
    for (long long i = (long long)(bx-16)*256 + tid; i < total4; i += stride){
        long long base = i*4;
        int s = (int)((base >> 9) & 2047);
        float w = dragon_w[s];
        const float4 k = *(const float4*)(K + base);
        ushort4 ko;
        ko.x = f2bf(k.x*w); ko.y = f2bf(k.y*w); ko.z = f2bf(k.z*w); ko.w = f2bf(k.w*w);
        *(ushort4*)(Kb + base) = ko;
    }
}

// ---------------------------------------------------------------------------
// GEMM 1: Sp[b,q,k] = bf16( exp( (Qb . Kb^T) / sqrt(512) ) )
// Round-0 proven structure: 128x128 tile, BK=64, 4 waves (2x2), 4x4 MFMA
// 16x16x32 per wave, XOR-swizzled LDS, 32 KiB -> 5 blocks/CU (implicit
// wave-level pipelining across blocks).
// New: (a) XCD-aware bijective block swizzle — 256 consecutive logical blocks
// = one batch per XCD, so Qb+Kb (4 MB) stays in that XCD's L2;
// (b) epilogue computes per-k-block row sums lpart[b][kb][q] of the ROUNDED
// bf16 exp values (softmax denominator), so k_gemm_pv's loop is a pure GEMM.
// ---------------------------------------------------------------------------
#define SCALE_QK 0.04419417382415922f

__global__ __launch_bounds__(256) void k_gemm_qk(
    const unsigned short* __restrict__ Qb, const unsigned short* __restrict__ Kb,
    unsigned short* __restrict__ Sp, float* __restrict__ lpart)
{
    __shared__ unsigned short At[128*64];
    __shared__ unsigned short Bt[128*64];
    int tid = threadIdx.x;
    int lane = tid & 63, wave = tid >> 6;
    int wm = wave >> 1, wn = wave & 1;
    int ln = lane & 15, q4 = lane >> 4;
    int sx = ln & 7;                      // fragment-row swizzle key
    // XCD swizzle (2048 % 8 == 0, bijective): lid runs x-fastest over
    // (kb, qb, b); 256 consecutive lids = one full batch -> one XCD.
    int lid = (blockIdx.x & 7)*256 + (blockIdx.x >> 3);
    int kb = lid & 15, qb = (lid >> 4) & 15, b = lid >> 8;
    int q0 = qb*128, k0 = kb*128;
    const unsigned short* Abase = Qb + ((long long)b*2048 + q0)*512;
    const unsigned short* Bbase = Kb + ((long long)b*2048 + k0)*512;

    f32x4 acc[4][4];
    #pragma unroll
    for (int i = 0; i < 4; ++i)
        #pragma unroll
        for (int j = 0; j < 4; ++j) acc[i][j] = (f32x4)0.0f;

    int cc = lane & 7;                    // staging chunk col (LDS side)
    int rg = lane >> 3;                   // staging row within 8-row group
    for (int kt = 0; kt < 8; ++kt){
        #pragma unroll
        for (int c = 0; c < 4; ++c){
            int chunk = wave*4 + c;                 // 16 x 1KB chunks per tile
            int row = chunk*8 + rg;
            int gc  = cc ^ (row & 7);               // swizzled source chunk
            gload_lds16(Abase + (long long)row*512 + kt*64 + gc*8, &At[chunk*512]);
            gload_lds16(Bbase + (long long)row*512 + kt*64 + gc*8, &Bt[chunk*512]);
        }
        __syncthreads();
        #pragma unroll
        for (int ks = 0; ks < 2; ++ks){
            s16x8 af[4], bfr[4];
            int cs = ((ks*4 + q4) ^ sx) * 8;        // swizzled fragment chunk
            #pragma unroll
            for (int i = 0; i < 4; ++i)
                af[i] = *(const s16x8*)&At[(wm*64 + i*16 + ln)*64 + cs];
            #pragma unroll
            for (int j = 0; j < 4; ++j)
                bfr[j] = *(const s16x8*)&Bt[(wn*64 + j*16 + ln)*64 + cs];
            #pragma unroll
            for (int i = 0; i < 4; ++i)
                #pragma unroll
                for (int j = 0; j < 4; ++j)
                    acc[i][j] = __builtin_amdgcn_mfma_f32_16x16x32_bf16(af[i], bfr[j], acc[i][j], 0, 0, 0);
        }
        __syncthreads();
    }
    // epilogue: exp, bf16 store, and per-k-block row sums of the ROUNDED
    // values (exactly what PV will multiply against)
    float* lred = (float*)At;              // [128][2], reuses LDS (no occ hit)
    unsigned short* outp = Sp + (long long)b*2048*2048;
    #pragma unroll
    for (int i = 0; i < 4; ++i){
        float rs[4] = {0.f, 0.f, 0.f, 0.f};
        #pragma unroll
        for (int j = 0; j < 4; ++j){
            #pragma unroll
            for (int r = 0; r < 4; ++r){
                int q = q0 + wm*64 + i*16 + q4*4 + r;   // C/D: row=(lane>>4)*4+reg
                int k = k0 + wn*64 + j*16 + ln;         //      col=lane&15
                float v = __expf(acc[i][j][r] * SCALE_QK);
                unsigned short h = f2bf(v);
                outp[(long long)q*2048 + k] = h;
                rs[r] += bf2f(h);
            }
        }
        #pragma unroll
        for (int r = 0; r < 4; ++r){
            float v = rs[r];
            v += __shfl_xor(v, 1, 16);
            v += __shfl_xor(v, 2, 16);
            v += __shfl_xor(v, 4, 16);
            v += __shfl_xor(v, 8, 16);
            if (ln == 0) lred[(wm*64 + i*16 + q4*4 + r)*2 + wn] = v;
        }
    }
    __syncthreads();
    if (tid < 128)
        lpart[((long long)b*16 + kb)*2048 + q0 + tid] = lred[tid*2] + lred[tid*2+1];
}

// ---------------------------------------------------------------------------
// GEMM 2: out[b,q,d] = blend * (Sp . V) / l[q] + (1-blend) * Vmean[d]
// Round-0 structure, 128x128, pure GEMM loop (l comes from lpart now).
// XCD swizzle: 4 d-sibling blocks (sharing the Sp A-panel) + one batch's
// Vt stay co-resident on one XCD's L2.
// ---------------------------------------------------------------------------
__global__ __launch_bounds__(256) void k_gemm_pv(
    const unsigned short* __restrict__ Sp, const unsigned short* __restrict__ Vt,
    const float* __restrict__ lpart, const float* __restrict__ vmean,
    const float* __restrict__ blendp, float* __restrict__ out)
{
    __shared__ unsigned short At[128*64];
    __shared__ unsigned short Bt[128*64];
    int tid = threadIdx.x;
    int lane = tid & 63, wave = tid >> 6;
    int wm = wave >> 1, wn = wave & 1;
    int ln = lane & 15, q4 = lane >> 4;
    int sx = ln & 7;
    // XCD swizzle (512 % 8 == 0): 64 consecutive lids = one batch per XCD.
    int lid = (blockIdx.x & 7)*64 + (blockIdx.x >> 3);
    int db = lid & 3, qb = (lid >> 2) & 15, b = lid >> 6;
    int q0 = qb*128, d0 = db*128;
    const unsigned short* Abase = Sp + (long long)b*2048*2048 + (long long)q0*2048;
    const unsigned short* Bbase = Vt + ((long long)b*512 + d0)*2048;

    f32x4 acc[4][4];
    #pragma unroll
    for (int i = 0; i < 4; ++i)
        #pragma unroll
        for (int j = 0; j < 4; ++j) acc[i][j] = (f32x4)0.0f;

    int cc = lane & 7;
    int rg = lane >> 3;
    for (int kt = 0; kt < 32; ++kt){
        #pragma unroll
        for (int c = 0; c < 4; ++c){
            int chunk = wave*4 + c;
            int row = chunk*8 + rg;
            int gc  = cc ^ (row & 7);
            gload_lds16(Abase + (long long)row*2048 + kt*64 + gc*8, &At[chunk*512]);
            gload_lds16(Bbase + (long long)row*2048 + kt*64 + gc*8, &Bt[chunk*512]);
        }
        __syncthreads();
        #pragma unroll
        for (int ks = 0; ks < 2; ++ks){
            s16x8 af[4], bfr[4];
            int cs = ((ks*4 + q4) ^ sx) * 8;
            #pragma unroll
            for (int i = 0; i < 4; ++i)
                af[i] = *(const s16x8*)&At[(wm*64 + i*16 + ln)*64 + cs];
            #pragma unroll
            for (int j = 0; j < 4; ++j)
                bfr[j] = *(const s16x8*)&Bt[(wn*64 + j*16 + ln)*64 + cs];
            #pragma unroll
            for (int i = 0; i < 4; ++i)
                #pragma unroll
                for (int j = 0; j < 4; ++j)
                    acc[i][j] = __builtin_amdgcn_mfma_f32_16x16x32_bf16(af[i], bfr[j], acc[i][j], 0, 0, 0);
        }
        __syncthreads();
    }

    // softmax denominator from qk's per-k-block partials
    float* l_sh = (float*)Bt;   // 128 floats, reuses LDS
    if (tid < 128){
        float s = 0.f;
        #pragma unroll
        for (int kb = 0; kb < 16; ++kb)
            s += lpart[((long long)b*16 + kb)*2048 + q0 + tid];
        l_sh[tid] = 1.0f / s;
    }
    __syncthreads();

    float blend = blendp[0];
    float ib = 1.0f - blend;
    float* obase = out + ((long long)b*2048 + q0)*512 + d0;
    float vm[4];
    #pragma unroll
    for (int j = 0; j < 4; ++j) vm[j] = vmean[b*512 + d0 + wn*64 + j*16 + ln];
    #pragma unroll
    for (int i = 0; i < 4; ++i){
        #pragma unroll
        for (int r = 0; r < 4; ++r){
            int ql = wm*64 + i*16 + q4*4 + r;
            float linv = l_sh[ql];
            #pragma unroll
            for (int j = 0; j < 4; ++j){
                int dl = wn*64 + j*16 + ln;
                obase[(long long)ql*512 + dl] = blend*acc[i][j][r]*linv + ib*vm[j];
            }
        }
    }
}

// ---------------------------------------------------------------------------
extern "C" void kernel_launch(void* const* d_in, const int* in_sizes, int n_in,
                              void* d_out, int out_size, void* d_ws, size_t ws_size,
                              hipStream_t stream)
{
    (void)in_sizes; (void)n_in; (void)out_size; (void)ws_size;
    const float* Q  = (const float*)d_in[0];
    const float* K  = (const float*)d_in[1];
    const float* V  = (const float*)d_in[2];
    const float* ps = (const float*)d_in[3];
    const float* pb = (const float*)d_in[4];
    const float* w1 = (const float*)d_in[5];
    const float* b1 = (const float*)d_in[6];
    const float* w2 = (const float*)d_in[7];
    const float* b2 = (const float*)d_in[8];
    float* out = (float*)d_out;

    char* ws = (char*)d_ws;
    float* dragon_w        = (float*)(ws);                                        // 8 KiB
    float* blend           = (float*)(ws + 8192);
    float* vmean           = (float*)(ws + 16384);                                // 16 KiB
    float* vmean_part      = (float*)(ws + 32768);                                // 512 KiB
    size_t off = 32768 + (size_t)512*1024;
    unsigned short* Qb     = (unsigned short*)(ws + off);                         // 16 MiB
    unsigned short* Kb     = (unsigned short*)(ws + off + (size_t)16*1024*1024);  // 16 MiB
    unsigned short* Vt     = (unsigned short*)(ws + off + (size_t)32*1024*1024);  // 16 MiB
    unsigned short* Sp     = (unsigned short*)(ws + off + (size_t)48*1024*1024);  // 64 MiB
    float* lpart           = (float*)(ws + off + (size_t)112*1024*1024);          // 1 MiB

    hipLaunchKernelGGL(k_stage1,  dim3(4097), dim3(256), 0, stream,
                       Q, V, ps, pb, w1, b1, w2, b2, dragon_w, blend, Qb, Vt, vmean_part);
    hipLaunchKernelGGL(k_stage2,  dim3(2064), dim3(256), 0, stream,
                       K, dragon_w, vmean_part, Kb, vmean);
    hipLaunchKernelGGL(k_gemm_qk, dim3(2048), dim3(256), 0, stream,
                       Qb, Kb, Sp, lpart);
    hipLaunchKernelGGL(k_gemm_pv, dim3(512),  dim3(256), 0, stream,
                       Sp, Vt, lpart, vmean, blend, out);
}

// Round 3
// 239.226 us; speedup vs baseline: 1.0886x; 1.0696x over previous
//
#include <hip/hip_runtime.h>
#include <cstdint>

#define DEV __device__ __forceinline__

typedef float f32x4 __attribute__((ext_vector_type(4)));
typedef short s16x8 __attribute__((ext_vector_type(8)));

DEV unsigned short f2bf(float f){
    unsigned u = __builtin_bit_cast(unsigned, f);
    u = u + 0x7fffu + ((u >> 16) & 1u);   // RNE
    return (unsigned short)(u >> 16);
}
DEV float bf2f(unsigned short h){
    unsigned u = ((unsigned)h) << 16;
    return __builtin_bit_cast(float, u);
}

typedef const void __attribute__((address_space(1)))* gcp;
typedef void __attribute__((address_space(3)))* lp;
DEV void gload_lds16(const void* g, void* l){
    // async global->LDS, 16B per lane; LDS dest = wave-uniform base + lane*16
    __builtin_amdgcn_global_load_lds((gcp)g, (lp)l, 16, 0, 0);
}

// ---------------------------------------------------------------------------
// Stage 1 (grid 6145):
//   block 0          : dragon pattern + blend scalar
//   blocks 1..2048   : Q -> bf16
//   blocks 2049..4096: K -> bf16 (UNSCALED; dragon_w applied in qk epilogue)
//   blocks 4097..    : V -> Vt (bf16 [b][d][s]) + race-free vmean partials
// ---------------------------------------------------------------------------
__global__ __launch_bounds__(256) void k_stage1(
    const float* __restrict__ Q, const float* __restrict__ K,
    const float* __restrict__ V,
    const float* __restrict__ scale, const float* __restrict__ bias,
    const float* __restrict__ w1, const float* __restrict__ b1,
    const float* __restrict__ w2, const float* __restrict__ b2,
    float* __restrict__ dragon_w, float* __restrict__ blend_out,
    unsigned short* __restrict__ Qb, unsigned short* __restrict__ Kb,
    unsigned short* __restrict__ Vt, float* __restrict__ vmean_part)
{
    __shared__ float sh[8704];
    int tid = threadIdx.x;
    int bx  = blockIdx.x;

    if (bx == 0){
        float* A    = sh;          // 4096
        float* Bb   = sh + 4096;   // 4096
        float* sred = sh + 8192;   // 512
        if (tid == 0) A[0] = 0.5f;
        __syncthreads();
        int len = 1;
        for (int it = 1; it < 12; ++it){
            int n = len, nl = 2*n + 1;
            for (int i = tid; i < nl; i += 256){
                float v;
                if (i < n)       v = A[i];
                else if (i == n) v = 0.5f;
                else             v = 1.0f - A[2*n - i];
                Bb[i] = v;
            }
            __syncthreads();
            const float third = 1.0f/3.0f;
            for (int i = tid; i < nl; i += 256){
                float s = Bb[i]*third;
                if (i > 0)    s += Bb[i-1]*third;
                if (i < nl-1) s += Bb[i+1]*third;
                A[i] = s;
            }
            __syncthreads();
            float mn = 3.4e38f, mx = -3.4e38f;
            for (int i = tid; i < nl; i += 256){ float v = A[i]; mn = fminf(mn,v); mx = fmaxf(mx,v); }
            sred[tid] = mn; sred[256 + tid] = mx;
            __syncthreads();
            for (int off = 128; off > 0; off >>= 1){
                if (tid < off){
                    sred[tid]       = fminf(sred[tid],       sred[tid+off]);
                    sred[256 + tid] = fmaxf(sred[256 + tid], sred[256 + tid + off]);
                }
                __syncthreads();
            }
            float lo = sred[0], den = sred[256] - lo + 1e-8f;
            for (int i = tid; i < nl; i += 256) A[i] = (A[i] - lo) / den;
            len = nl;
            __syncthreads();
        }
        float sc = scale[11], bi = bias[11];
        for (int i = tid; i < 2048; i += 256){
            float x = A[2*i]*sc + bi;
            dragon_w[i] = fmaxf(x, 0.f) + log1pf(__expf(-fabsf(x)));  // softplus
        }
        if (tid < 64){
            float h = fmaxf(w1[11*64 + tid] + b1[tid], 0.f);
            float c = h * w2[tid];
            for (int off = 32; off > 0; off >>= 1) c += __shfl_xor(c, off, 64);
            if (tid == 0) blend_out[0] = 1.f/(1.f + __expf(-(c + b2[0])));
        }
        return;
    }

    if (bx <= 4096){
        // ---- Q (1..2048) / K (2049..4096) -> bf16, no scaling ----
        const float* src = (bx <= 2048) ? Q : K;
        unsigned short* dst = (bx <= 2048) ? Qb : Kb;
        int bi = (bx <= 2048) ? (bx-1) : (bx-2049);
        const long long total4 = (long long)8*2048*512/4;   // 2097152
        long long stride = 2048LL*256;
        for (long long i = (long long)bi*256 + tid; i < total4; i += stride){
            long long base = i*4;
            const float4 q = *(const float4*)(src + base);
            ushort4 qo;
            qo.x = f2bf(q.x); qo.y = f2bf(q.y); qo.z = f2bf(q.z); qo.w = f2bf(q.w);
            *(ushort4*)(dst + base) = qo;
        }
        return;
    }

    // ---- V transpose + vmean partials ----
    int t = bx - 4097;                    // 0..2047 = 32 stile x 8 dtile x 8 b
    int stile = t & 31, dtile = (t >> 5) & 7, b = t >> 8;
    int s0 = stile*64, d0 = dtile*64;
    float (*tile)[67] = (float(*)[67])sh;  // 64x67 floats = 4288
    float* red = sh + 4288;                // 256 floats
    int c4 = tid & 15, rr = tid >> 4;
    const float* src = V + ((long long)b*2048 + s0)*512 + d0;
    #pragma unroll
    for (int p = 0; p < 4; ++p){
        int row = p*16 + rr;
        const float4 v = *(const float4*)(src + (long long)row*512 + c4*4);
        tile[row][c4*4+0] = v.x; tile[row][c4*4+1] = v.y;
        tile[row][c4*4+2] = v.z; tile[row][c4*4+3] = v.w;
    }
    __syncthreads();
    unsigned short* dst = Vt + ((long long)b*512 + d0)*2048 + s0;
    #pragma unroll
    for (int p = 0; p < 4; ++p){
        int d = p*16 + rr;
        ushort4 o;
        o.x = f2bf(tile[c4*4+0][d]);
        o.y = f2bf(tile[c4*4+1][d]);
        o.z = f2bf(tile[c4*4+2][d]);
        o.w = f2bf(tile[c4*4+3][d]);
        *(ushort4*)(dst + (long long)d*2048 + c4*4) = o;
    }
    int dcol = tid & 63, sp = tid >> 6;
    float s = 0.f;
    #pragma unroll
    for (int ii = 0; ii < 16; ++ii) s += tile[sp*16 + ii][dcol];
    red[sp*64 + dcol] = s;
    __syncthreads();
    if (sp == 0){
        float tot = red[dcol] + red[64+dcol] + red[128+dcol] + red[192+dcol];
        vmean_part[stile*4096 + b*512 + d0 + dcol] = tot * (1.0f/2048.0f);
    }
}

// ---------------------------------------------------------------------------
// GEMM 1: Sp[b,q,k] = bf16( exp( w[k] * (Qb . Kb^T) / sqrt(512) ) )
// 128x128 tile, BK=64, 4 waves (2x2), XOR-swizzled LDS.
// NEW: 2-phase explicit double-buffer — stage tile t+1 into the other 32-KiB
// buffer BEFORE computing tile t; one __syncthreads per K-step (its vmcnt(0)
// drain now lands after a full MFMA phase of slack, not zero). 64 KiB LDS ->
// 2 blocks/CU. dragon_w applied as f32 per-column scale in the epilogue.
// Epilogue also writes per-k-block softmax-denominator partials lpart.
// XCD-aware bijective swizzle: 256 consecutive lids = one batch per XCD.
// ---------------------------------------------------------------------------
#define SCALE_QK 0.04419417382415922f

__global__ __launch_bounds__(256) void k_gemm_qk(
    const unsigned short* __restrict__ Qb, const unsigned short* __restrict__ Kb,
    const float* __restrict__ dragon_w,
    unsigned short* __restrict__ Sp, float* __restrict__ lpart)
{
    __shared__ unsigned short A0[128*64], B0[128*64];
    __shared__ unsigned short A1[128*64], B1[128*64];
    int tid = threadIdx.x;
    int lane = tid & 63, wave = tid >> 6;
    int wm = wave >> 1, wn = wave & 1;
    int ln = lane & 15, q4 = lane >> 4;
    int sx = ln & 7;
    int lid = (blockIdx.x & 7)*256 + (blockIdx.x >> 3);
    int kb = lid & 15, qb = (lid >> 4) & 15, b = lid >> 8;
    int q0 = qb*128, k0 = kb*128;
    const unsigned short* Abase = Qb + ((long long)b*2048 + q0)*512;
    const unsigned short* Bbase = Kb + ((long long)b*2048 + k0)*512;

    f32x4 acc[4][4];
    #pragma unroll
    for (int i = 0; i < 4; ++i)
        #pragma unroll
        for (int j = 0; j < 4; ++j) acc[i][j] = (f32x4)0.0f;

    int cc = lane & 7;
    int rg = lane >> 3;

    auto STAGE = [&](unsigned short* dA, unsigned short* dB, int kt){
        #pragma unroll
        for (int c = 0; c < 4; ++c){
            int chunk = wave*4 + c;
            int row = chunk*8 + rg;
            int gc  = cc ^ (row & 7);
            gload_lds16(Abase + (long long)row*512 + kt*64 + gc*8, dA + chunk*512);
            gload_lds16(Bbase + (long long)row*512 + kt*64 + gc*8, dB + chunk*512);
        }
    };
    auto COMPUTE = [&](const unsigned short* At, const unsigned short* Bt){
        #pragma unroll
        for (int ks = 0; ks < 2; ++ks){
            s16x8 af[4], bfr[4];
            int cs = ((ks*4 + q4) ^ sx) * 8;
            #pragma unroll
            for (int i = 0; i < 4; ++i)
                af[i] = *(const s16x8*)&At[(wm*64 + i*16 + ln)*64 + cs];
            #pragma unroll
            for (int j = 0; j < 4; ++j)
                bfr[j] = *(const s16x8*)&Bt[(wn*64 + j*16 + ln)*64 + cs];
            #pragma unroll
            for (int i = 0; i < 4; ++i)
                #pragma unroll
                for (int j = 0; j < 4; ++j)
                    acc[i][j] = __builtin_amdgcn_mfma_f32_16x16x32_bf16(af[i], bfr[j], acc[i][j], 0, 0, 0);
        }
    };

    STAGE(A0, B0, 0); __syncthreads();
    STAGE(A1, B1, 1); COMPUTE(A0, B0); __syncthreads();
    STAGE(A0, B0, 2); COMPUTE(A1, B1); __syncthreads();
    STAGE(A1, B1, 3); COMPUTE(A0, B0); __syncthreads();
    STAGE(A0, B0, 4); COMPUTE(A1, B1); __syncthreads();
    STAGE(A1, B1, 5); COMPUTE(A0, B0); __syncthreads();
    STAGE(A0, B0, 6); COMPUTE(A1, B1); __syncthreads();
    STAGE(A1, B1, 7); COMPUTE(A0, B0); __syncthreads();
    COMPUTE(A1, B1); __syncthreads();

    // epilogue: per-column dragon weight (f32), exp, bf16 store, row-sum
    // partials of the ROUNDED values (exactly what PV multiplies against)
    float wj[4];
    #pragma unroll
    for (int j = 0; j < 4; ++j)
        wj[j] = dragon_w[k0 + wn*64 + j*16 + ln] * SCALE_QK;

    float* lred = (float*)A0;              // [128][2], reuses LDS
    unsigned short* outp = Sp + (long long)b*2048*2048;
    #pragma unroll
    for (int i = 0; i < 4; ++i){
        float rs[4] = {0.f, 0.f, 0.f, 0.f};
        #pragma unroll
        for (int j = 0; j < 4; ++j){
            #pragma unroll
            for (int r = 0; r < 4; ++r){
                int q = q0 + wm*64 + i*16 + q4*4 + r;   // C/D: row=(lane>>4)*4+reg
                int k = k0 + wn*64 + j*16 + ln;         //      col=lane&15
                float v = __expf(acc[i][j][r] * wj[j]);
                unsigned short h = f2bf(v);
                outp[(long long)q*2048 + k] = h;
                rs[r] += bf2f(h);
            }
        }
        #pragma unroll
        for (int r = 0; r < 4; ++r){
            float v = rs[r];
            v += __shfl_xor(v, 1, 16);
            v += __shfl_xor(v, 2, 16);
            v += __shfl_xor(v, 4, 16);
            v += __shfl_xor(v, 8, 16);
            if (ln == 0) lred[(wm*64 + i*16 + q4*4 + r)*2 + wn] = v;
        }
    }
    __syncthreads();
    if (tid < 128)
        lpart[((long long)b*16 + kb)*2048 + q0 + tid] = lred[tid*2] + lred[tid*2+1];
}

// ---------------------------------------------------------------------------
// GEMM 2: out[b,q,d] = blend * (Sp . V) / l[q] + (1-blend) * Vmean[d]
// Same 2-phase double-buffered schedule; pure GEMM loop. l[q] from lpart;
// Vmean reduced from vmean_part in the epilogue (stage2 eliminated).
// Grid 512 = exactly 2 blocks/CU at 64 KiB LDS.
// ---------------------------------------------------------------------------
__global__ __launch_bounds__(256) void k_gemm_pv(
    const unsigned short* __restrict__ Sp, const unsigned short* __restrict__ Vt,
    const float* __restrict__ lpart, const float* __restrict__ vmean_part,
    const float* __restrict__ blendp, float* __restrict__ out)
{
    __shared__ unsigned short A0[128*64], B0[128*64];
    __shared__ unsigned short A1[128*64], B1[128*64];
    int tid = threadIdx.x;
    int lane = tid & 63, wave = tid >> 6;
    int wm = wave >> 1, wn = wave & 1;
    int ln = lane & 15, q4 = lane >> 4;
    int sx = ln & 7;
    int lid = (blockIdx.x & 7)*64 + (blockIdx.x >> 3);
    int db = lid & 3, qb = (lid >> 2) & 15, b = lid >> 6;
    int q0 = qb*128, d0 = db*128;
    const unsigned short* Abase = Sp + (long long)b*2048*2048 + (long long)q0*2048;
    const unsigned short* Bbase = Vt + ((long long)b*512 + d0)*2048;

    f32x4 acc[4][4];
    #pragma unroll
    for (int i = 0; i < 4; ++i)
        #pragma unroll
        for (int j = 0; j < 4; ++j) acc[i][j] = (f32x4)0.0f;

    int cc = lane & 7;
    int rg = lane >> 3;

    auto STAGE = [&](unsigned short* dA, unsigned short* dB, int kt){
        #pragma unroll
        for (int c = 0; c < 4; ++c){
            int chunk = wave*4 + c;
            int row = chunk*8 + rg;
            int gc  = cc ^ (row & 7);
            gload_lds16(Abase + (long long)row*2048 + kt*64 + gc*8, dA + chunk*512);
            gload_lds16(Bbase + (long long)row*2048 + kt*64 + gc*8, dB + chunk*512);
        }
    };
    auto COMPUTE = [&](const unsigned short* At, const unsigned short* Bt){
        #pragma unroll
        for (int ks = 0; ks < 2; ++ks){
            s16x8 af[4], bfr[4];
            int cs = ((ks*4 + q4) ^ sx) * 8;
            #pragma unroll
            for (int i = 0; i < 4; ++i)
                af[i] = *(const s16x8*)&At[(wm*64 + i*16 + ln)*64 + cs];
            #pragma unroll
            for (int j = 0; j < 4; ++j)
                bfr[j] = *(const s16x8*)&Bt[(wn*64 + j*16 + ln)*64 + cs];
            #pragma unroll
            for (int i = 0; i < 4; ++i)
                #pragma unroll
                for (int j = 0; j < 4; ++j)
                    acc[i][j] = __builtin_amdgcn_mfma_f32_16x16x32_bf16(af[i], bfr[j], acc[i][j], 0, 0, 0);
        }
    };

    STAGE(A0, B0, 0); __syncthreads();
    for (int kt = 0; kt < 16; ++kt){
        STAGE(A1, B1, 2*kt + 1);
        COMPUTE(A0, B0); __syncthreads();
        if (kt < 15) STAGE(A0, B0, 2*kt + 2);
        COMPUTE(A1, B1); __syncthreads();
    }

    // softmax denominator + vmean, both reduced into LDS
    float* l_sh  = (float*)A0;   // 128 floats
    float* vm_sh = (float*)B0;   // 128 floats
    if (tid < 128){
        float s = 0.f;
        #pragma unroll
        for (int kb = 0; kb < 16; ++kb)
            s += lpart[((long long)b*16 + kb)*2048 + q0 + tid];
        l_sh[tid] = 1.0f / s;
    } else {
        int d = tid - 128;
        float s = 0.f;
        #pragma unroll
        for (int st = 0; st < 32; ++st)
            s += vmean_part[st*4096 + b*512 + d0 + d];
        vm_sh[d] = s;
    }
    __syncthreads();

    float blend = blendp[0];
    float ib = 1.0f - blend;
    float* obase = out + ((long long)b*2048 + q0)*512 + d0;
    float vm[4];
    #pragma unroll
    for (int j = 0; j < 4; ++j) vm[j] = vm_sh[wn*64 + j*16 + ln];
    #pragma unroll
    for (int i = 0; i < 4; ++i){
        #pragma unroll
        for (int r = 0; r < 4; ++r){
            int ql = wm*64 + i*16 + q4*4 + r;
            float linv = l_sh[ql];
            #pragma unroll
            for (int j = 0; j < 4; ++j){
                int dl = wn*64 + j*16 + ln;
                obase[(long long)ql*512 + dl] = blend*acc[i][j][r]*linv + ib*vm[j];
            }
        }
    }
}

// ---------------------------------------------------------------------------
extern "C" void kernel_launch(void* const* d_in, const int* in_sizes, int n_in,
                              void* d_out, int out_size, void* d_ws, size_t ws_size,
                              hipStream_t stream)
{
    (void)in_sizes; (void)n_in; (void)out_size; (void)ws_size;
    const float* Q  = (const float*)d_in[0];
    const float* K  = (const float*)d_in[1];
    const float* V  = (const float*)d_in[2];
    const float* ps = (const float*)d_in[3];
    const float* pb = (const float*)d_in[4];
    const float* w1 = (const float*)d_in[5];
    const float* b1 = (const float*)d_in[6];
    const float* w2 = (const float*)d_in[7];
    const float* b2 = (const float*)d_in[8];
    float* out = (float*)d_out;

    char* ws = (char*)d_ws;
    float* dragon_w        = (float*)(ws);                                        // 8 KiB
    float* blend           = (float*)(ws + 8192);
    float* vmean_part      = (float*)(ws + 32768);                                // 512 KiB
    size_t off = 32768 + (size_t)512*1024;
    unsigned short* Qb     = (unsigned short*)(ws + off);                         // 16 MiB
    unsigned short* Kb     = (unsigned short*)(ws + off + (size_t)16*1024*1024);  // 16 MiB
    unsigned short* Vt     = (unsigned short*)(ws + off + (size_t)32*1024*1024);  // 16 MiB
    unsigned short* Sp     = (unsigned short*)(ws + off + (size_t)48*1024*1024);  // 64 MiB
    float* lpart           = (float*)(ws + off + (size_t)112*1024*1024);          // 1 MiB

    hipLaunchKernelGGL(k_stage1,  dim3(6145), dim3(256), 0, stream,
                       Q, K, V, ps, pb, w1, b1, w2, b2, dragon_w, blend,
                       Qb, Kb, Vt, vmean_part);
    hipLaunchKernelGGL(k_gemm_qk, dim3(2048), dim3(256), 0, stream,
                       Qb, Kb, dragon_w, Sp, lpart);
    hipLaunchKernelGGL(k_gemm_pv, dim3(512),  dim3(256), 0, stream,
                       Sp, Vt, lpart, vmean_part, blend, out);
}